// Round 4
// baseline (132.893 us; speedup 1.0000x reference)
//
#include <hip/hip_runtime.h>
#include <hip/hip_bf16.h>

// Sparse bottleneck block, B=32, Cin=Cout=256, width=64, H=W=56. f32 in/out.
// Round 4: k1 -> LDS-staged MFMA (dwordx4 global, ds_read_b128 frags, exact
// f32 mask); k2+k3 fused via LDS h2 tile (no h2 HBM round-trip).
// Pipeline: kbn | kw | k1_mfma | k1b | k23.
// ws: h1g bf16 [32][58][58][64] | mask f32 [32][3136] | w1p/w2p/w3p | tabs

#define BATCH 32
#define CIN   256
#define WIDTH 64
#define COUT  256
#define HH    56
#define WW    56
#define HW    3136
#define EPS   1e-5f

typedef __attribute__((ext_vector_type(8))) short bf16x8;
typedef __attribute__((ext_vector_type(4))) float f32x4;

static __device__ __forceinline__ unsigned short f2bf(float f) {
    __hip_bfloat16 h = __float2bfloat16(f);
    return *reinterpret_cast<unsigned short*>(&h);
}

// ---------------------------------------------------------------------------
// kbn: bn scale/shift tables. tabs: sc1[64] sh1[64] sc2[64] sh2[64] sc3[256] sh3[256]
// ---------------------------------------------------------------------------
__global__ __launch_bounds__(384) void kbn(
    const float* __restrict__ g1, const float* __restrict__ b1,
    const float* __restrict__ m1, const float* __restrict__ v1,
    const float* __restrict__ g2, const float* __restrict__ b2,
    const float* __restrict__ m2, const float* __restrict__ v2,
    const float* __restrict__ g3, const float* __restrict__ b3,
    const float* __restrict__ m3, const float* __restrict__ v3,
    float* __restrict__ tabs)
{
    int t = threadIdx.x;
    if (t < 64) {
        float sc = g1[t] * rsqrtf(v1[t] + EPS);
        tabs[t] = sc; tabs[64 + t] = b1[t] - m1[t] * sc;
    } else if (t < 128) {
        int o = t - 64;
        float sc = g2[o] * rsqrtf(v2[o] + EPS);
        tabs[128 + o] = sc; tabs[192 + o] = b2[o] - m2[o] * sc;
    } else if (t < 384) {
        int o = t - 128;
        float sc = g3[o] * rsqrtf(v3[o] + EPS);
        tabs[256 + o] = sc; tabs[512 + o] = b3[o] - m3[o] * sc;
    }
}

// ---------------------------------------------------------------------------
// kw: pack w1 [64][256], w2 [64][64][3][3], w3 [256][64] into bf16 A-frags.
// Frag layout (all): o = mt*16 + (l&15); c = ck*32 + (l>>4)*8 + j
// ---------------------------------------------------------------------------
__global__ __launch_bounds__(256) void kw_pack(
    const float* __restrict__ w1, const float* __restrict__ w2,
    const float* __restrict__ w3, __hip_bfloat16* __restrict__ w1p,
    __hip_bfloat16* __restrict__ w2p, __hip_bfloat16* __restrict__ w3p)
{
    int idx = blockIdx.x * 256 + threadIdx.x;
    if (idx < 16384) {                       // w1p: kt 0..7, mt 0..3
        int j = idx & 7, l = (idx >> 3) & 63;
        int mt = (idx >> 9) & 3, kt = idx >> 11;
        int o = mt * 16 + (l & 15);
        int c = kt * 32 + (l >> 4) * 8 + j;
        *reinterpret_cast<unsigned short*>(w1p + idx) = f2bf(w1[o * CIN + c]);
    } else if (idx < 16384 + 36864) {        // w2p: tap 0..8, kt 0..1, mt 0..3
        int i2 = idx - 16384;
        int j = i2 & 7, l = (i2 >> 3) & 63;
        int mt = (i2 >> 9) & 3, kt = (i2 >> 11) & 1, tap = i2 >> 12;
        int o = mt * 16 + (l & 15);
        int c = kt * 32 + (l >> 4) * 8 + j;
        *reinterpret_cast<unsigned short*>(w2p + i2) =
            f2bf(w2[(o * WIDTH + c) * 9 + tap]);
    } else if (idx < 16384 + 36864 + 16384) { // w3p: kt 0..1, mt 0..15
        int i3 = idx - 16384 - 36864;
        int j = i3 & 7, l = (i3 >> 3) & 63;
        int mt = (i3 >> 9) & 15, kt = i3 >> 13;
        int o = mt * 16 + (l & 15);
        int c = kt * 32 + (l >> 4) * 8 + j;
        *reinterpret_cast<unsigned short*>(w3p + i3) = f2bf(w3[o * WIDTH + c]);
    }
}

// ---------------------------------------------------------------------------
// k1: h1g = relu(bn1(conv1(x))) bf16 chan-last padded [58][58][64]; f32 mask.
// Block 256 thr (4 waves), 64 px, all 64 oc. K=256 in 8 chunks of 32.
// Stage x chunk -> LDS bf16 [px(64)][ch(32)] (double-buffered); stager
// accumulates f32 mask partials pre-conversion. Frags via ds_read_b128.
// Wave w computes px slice w*16..w*16+15 (all 64 oc).
// ---------------------------------------------------------------------------
__global__ __launch_bounds__(256) void k1_mfma(
    const float* __restrict__ x, const __hip_bfloat16* __restrict__ w1p,
    const float* __restrict__ sc1, const float* __restrict__ sh1,
    const float* __restrict__ mw, const float* __restrict__ mb,
    __hip_bfloat16* __restrict__ h1g, float* __restrict__ mask)
{
    __shared__ __align__(16) unsigned short xs[2][2048];  // [buf][px*32+ch]
    __shared__ __align__(16) float mtab[16][68];

    const int tid = threadIdx.x;
    const int l = tid & 63, w = tid >> 6;
    const int ln = l & 15, lg = l >> 4;
    const int b = blockIdx.y;
    const int px0 = blockIdx.x * 64;
    const float* __restrict__ xb = x + (size_t)b * CIN * HW;
    const bf16x8* __restrict__ w1v = reinterpret_cast<const bf16x8*>(w1p);

    const int chA = tid >> 4;          // 0..15
    const int pxs = (tid & 15) * 4;    // 0..60
    float msum[4] = {0.f, 0.f, 0.f, 0.f};

    // stage chunk kt into buffer bufi (also accumulate f32 mask partials)
    auto STAGE = [&](int kt, int bufi) {
        const float* xr = xb + (size_t)(kt * 32 + chA) * HW + px0 + pxs;
        float4 va = *reinterpret_cast<const float4*>(xr);
        float4 vb = *reinterpret_cast<const float4*>(xr + (size_t)16 * HW);
        float mwa = mw[kt * 32 + chA], mwb = mw[kt * 32 + 16 + chA];
        msum[0] += va.x * mwa + vb.x * mwb;
        msum[1] += va.y * mwa + vb.y * mwb;
        msum[2] += va.z * mwa + vb.z * mwb;
        msum[3] += va.w * mwa + vb.w * mwb;
        unsigned base = (unsigned)pxs * 32 + chA;
        xs[bufi][base +  0] = f2bf(va.x); xs[bufi][base + 32] = f2bf(va.y);
        xs[bufi][base + 64] = f2bf(va.z); xs[bufi][base + 96] = f2bf(va.w);
        xs[bufi][base + 16 +  0] = f2bf(vb.x); xs[bufi][base + 16 + 32] = f2bf(vb.y);
        xs[bufi][base + 16 + 64] = f2bf(vb.z); xs[bufi][base + 16 + 96] = f2bf(vb.w);
    };

    f32x4 acc[4];
    #pragma unroll
    for (int m = 0; m < 4; ++m) acc[m] = f32x4{0.f, 0.f, 0.f, 0.f};

    STAGE(0, 0);
    __syncthreads();

    const unsigned fidx = (unsigned)(w * 16 + ln) * 32 + lg * 8;
    #pragma unroll
    for (int kt = 0; kt < 8; ++kt) {
        const int cur = kt & 1;
        if (kt < 7) STAGE(kt + 1, cur ^ 1);
        bf16x8 bfr = *reinterpret_cast<const bf16x8*>(&xs[cur][fidx]);
        #pragma unroll
        for (int mt = 0; mt < 4; ++mt) {
            bf16x8 a = w1v[(kt * 4 + mt) * 64 + l];
            acc[mt] = __builtin_amdgcn_mfma_f32_16x16x32_bf16(a, bfr, acc[mt], 0, 0, 0);
        }
        __syncthreads();
    }

    // mask: table reduce over the 16 channel groups
    *reinterpret_cast<float4*>(&mtab[chA][pxs]) =
        make_float4(msum[0], msum[1], msum[2], msum[3]);
    __syncthreads();
    if (tid < 64) {
        float s = 0.f;
        #pragma unroll
        for (int g = 0; g < 16; ++g) s += mtab[g][tid];
        mask[b * HW + px0 + tid] = (s + mb[0] >= 0.f) ? 1.f : 0.f;
    }

    // epilogue: D[oc = mt*16 + lg*4 + jj][px = w*16 + ln]
    const int p = px0 + w * 16 + ln;
    const int y = p / 56, xcn = p - y * 56;
    const size_t base = (((size_t)b * 58 + y + 1) * 58 + (xcn + 1)) * 64 + lg * 4;
    #pragma unroll
    for (int mt = 0; mt < 4; ++mt) {
        int ob = mt * 16 + lg * 4;
        ushort4 u;
        u.x = f2bf(fmaxf(acc[mt][0] * sc1[ob + 0] + sh1[ob + 0], 0.f));
        u.y = f2bf(fmaxf(acc[mt][1] * sc1[ob + 1] + sh1[ob + 1], 0.f));
        u.z = f2bf(fmaxf(acc[mt][2] * sc1[ob + 2] + sh1[ob + 2], 0.f));
        u.w = f2bf(fmaxf(acc[mt][3] * sc1[ob + 3] + sh1[ob + 3], 0.f));
        *reinterpret_cast<ushort4*>(h1g + base + mt * 16) = u;
    }
}

// ---------------------------------------------------------------------------
// k1b: zero h1g where dilated mask == 0, and zero the 1-px pad border.
// ---------------------------------------------------------------------------
__global__ __launch_bounds__(256) void k1b_dilate(
    const float* __restrict__ mask, __hip_bfloat16* __restrict__ h1g)
{
    int idx = blockIdx.x * 256 + threadIdx.x;
    if (idx >= BATCH * 58 * 58) return;
    int b   = idx / 3364;
    int rem = idx - b * 3364;
    int r = rem / 58, c = rem - r * 58;

    bool zero;
    if (r == 0 || r == 57 || c == 0 || c == 57) {
        zero = true;
    } else {
        int y = r - 1, x = c - 1;
        float mx = 0.f;
        #pragma unroll
        for (int dy = -1; dy <= 1; ++dy)
            #pragma unroll
            for (int dx = -1; dx <= 1; ++dx) {
                int yy = y + dy, xx = x + dx;
                if (yy >= 0 && yy < HH && xx >= 0 && xx < WW)
                    mx = fmaxf(mx, mask[b * HW + yy * WW + xx]);
            }
        zero = (mx < 0.5f);
    }
    if (zero) {
        uint4 z = make_uint4(0u, 0u, 0u, 0u);
        uint4* p = reinterpret_cast<uint4*>(h1g + (size_t)idx * 64);
        #pragma unroll
        for (int k = 0; k < 8; ++k) p[k] = z;
    }
}

// ---------------------------------------------------------------------------
// k23: fused conv2(+bn2,relu,*mask) -> LDS bf16 h2 tile -> conv3(+bn3,*mask,
// +residual, relu) -> out. Block: image b, 2 output rows. Phase A = proven
// round-3 k2 main loop; h2 tile kept in LDS [row][px(64)][oc(64)] with
// oc-bit5 XOR px-parity swizzle. Phase B: wave w -> oc2 = w*64..+63.
// ---------------------------------------------------------------------------
__global__ __launch_bounds__(256) void k23(
    const __hip_bfloat16* __restrict__ h1g,
    const __hip_bfloat16* __restrict__ w2p,
    const __hip_bfloat16* __restrict__ w3p,
    const float* __restrict__ sc2, const float* __restrict__ sh2,
    const float* __restrict__ sc3, const float* __restrict__ sh3,
    const float* __restrict__ x, const float* __restrict__ mask,
    float* __restrict__ out)
{
    __shared__ __align__(16) unsigned short h2s[2][4096];

    const int tid = threadIdx.x;
    const int l = tid & 63, w = tid >> 6;
    const int b = blockIdx.y;
    const int r0 = blockIdx.x * 2;
    const int yrow = r0 + (w & 1);
    const int mh = w >> 1;
    const int ln = l & 15, lg = l >> 4;

    const bf16x8* __restrict__ h1v = reinterpret_cast<const bf16x8*>(h1g)
                                   + (size_t)b * (58 * 58 * 8);
    const bf16x8* __restrict__ w2v = reinterpret_cast<const bf16x8*>(w2p);
    const bf16x8* __restrict__ w3v = reinterpret_cast<const bf16x8*>(w3p);

    // ---------------- Phase A: conv2 ----------------
    f32x4 acc[2][4];
    #pragma unroll
    for (int i = 0; i < 2; ++i)
        #pragma unroll
        for (int j = 0; j < 4; ++j) acc[i][j] = f32x4{0.f, 0.f, 0.f, 0.f};

    #pragma unroll
    for (int dy = 0; dy < 3; ++dy) {
        const int rr = yrow + dy;
        #pragma unroll
        for (int dx = 0; dx < 3; ++dx) {
            const int tap = dy * 3 + dx;
            #pragma unroll
            for (int kt = 0; kt < 2; ++kt) {
                bf16x8 a0 = w2v[((tap * 2 + kt) * 4 + mh * 2 + 0) * 64 + l];
                bf16x8 a1 = w2v[((tap * 2 + kt) * 4 + mh * 2 + 1) * 64 + l];
                bf16x8 bf[4];
                #pragma unroll
                for (int nt = 0; nt < 4; ++nt) {
                    int colp = nt * 16 + ln + dx;
                    bf[nt] = h1v[(rr * 58 + colp) * 8 + kt * 4 + lg];
                }
                #pragma unroll
                for (int nt = 0; nt < 4; ++nt) {
                    acc[0][nt] = __builtin_amdgcn_mfma_f32_16x16x32_bf16(
                        a0, bf[nt], acc[0][nt], 0, 0, 0);
                    acc[1][nt] = __builtin_amdgcn_mfma_f32_16x16x32_bf16(
                        a1, bf[nt], acc[1][nt], 0, 0, 0);
                }
            }
        }
    }

    // h2 tile -> LDS (bn2 + relu + *mask; px>=56 written as zero)
    const int row = w & 1;
    #pragma unroll
    for (int nt = 0; nt < 4; ++nt) {
        int px = nt * 16 + ln;
        float mkv = (px < WW) ? mask[b * HW + yrow * WW + px] : 0.f;
        #pragma unroll
        for (int mi = 0; mi < 2; ++mi) {
            int ocb = (mh * 2 + mi) * 16 + lg * 4;
            ushort4 u;
            u.x = f2bf(fmaxf(acc[mi][nt][0] * sc2[ocb + 0] + sh2[ocb + 0], 0.f) * mkv);
            u.y = f2bf(fmaxf(acc[mi][nt][1] * sc2[ocb + 1] + sh2[ocb + 1], 0.f) * mkv);
            u.z = f2bf(fmaxf(acc[mi][nt][2] * sc2[ocb + 2] + sh2[ocb + 2], 0.f) * mkv);
            u.w = f2bf(fmaxf(acc[mi][nt][3] * sc2[ocb + 3] + sh2[ocb + 3], 0.f) * mkv);
            unsigned off = (unsigned)px * 64 + ((((unsigned)ocb >> 5) ^ (px & 1)) << 5)
                         + (ocb & 31);
            *reinterpret_cast<ushort4*>(&h2s[row][off]) = u;
        }
    }
    __syncthreads();

    // ---------------- Phase B: conv3 + residual ----------------
    const int ocw = w * 64;
    #pragma unroll
    for (int rw = 0; rw < 2; ++rw) {
        const int yr = r0 + rw;
        f32x4 acc3[4][4];
        #pragma unroll
        for (int m = 0; m < 4; ++m)
            #pragma unroll
            for (int n = 0; n < 4; ++n) acc3[m][n] = f32x4{0.f, 0.f, 0.f, 0.f};

        #pragma unroll
        for (int kt = 0; kt < 2; ++kt) {
            bf16x8 bfr[4];
            #pragma unroll
            for (int nt = 0; nt < 4; ++nt) {
                int px = nt * 16 + ln;
                unsigned off = (unsigned)px * 64 + ((unsigned)(kt ^ (px & 1)) << 5)
                             + lg * 8;
                bfr[nt] = *reinterpret_cast<const bf16x8*>(&h2s[rw][off]);
            }
            #pragma unroll
            for (int mt = 0; mt < 4; ++mt) {
                bf16x8 a = w3v[(kt * 16 + w * 4 + mt) * 64 + l];
                #pragma unroll
                for (int nt = 0; nt < 4; ++nt)
                    acc3[mt][nt] = __builtin_amdgcn_mfma_f32_16x16x32_bf16(
                        a, bfr[nt], acc3[mt][nt], 0, 0, 0);
            }
        }

        float mk[4];
        #pragma unroll
        for (int nt = 0; nt < 4; ++nt) {
            int px = nt * 16 + ln;
            mk[nt] = (px < WW) ? mask[b * HW + yr * WW + px] : 0.f;
        }
        #pragma unroll
        for (int mt = 0; mt < 4; ++mt) {
            #pragma unroll
            for (int jj = 0; jj < 4; ++jj) {
                int o = ocw + mt * 16 + lg * 4 + jj;
                float sc = sc3[o], sh = sh3[o];
                #pragma unroll
                for (int nt = 0; nt < 4; ++nt) {
                    int px = nt * 16 + ln;
                    if (px < WW) {
                        size_t idx = ((size_t)b * COUT + o) * HW + yr * WW + px;
                        float hv = (acc3[mt][nt][jj] * sc + sh) * mk[nt];
                        out[idx] = fmaxf(x[idx] + hv, 0.f);
                    }
                }
            }
        }
    }
}

// ---------------------------------------------------------------------------
extern "C" void kernel_launch(void* const* d_in, const int* in_sizes, int n_in,
                              void* d_out, int out_size, void* d_ws, size_t ws_size,
                              hipStream_t stream)
{
    const float* x  = (const float*)d_in[0];
    const float* w1 = (const float*)d_in[1];
    const float* w2 = (const float*)d_in[2];
    const float* w3 = (const float*)d_in[3];
    const float* g1 = (const float*)d_in[4];
    const float* b1 = (const float*)d_in[5];
    const float* m1 = (const float*)d_in[6];
    const float* v1 = (const float*)d_in[7];
    const float* g2 = (const float*)d_in[8];
    const float* b2 = (const float*)d_in[9];
    const float* m2 = (const float*)d_in[10];
    const float* v2 = (const float*)d_in[11];
    const float* g3 = (const float*)d_in[12];
    const float* b3 = (const float*)d_in[13];
    const float* m3 = (const float*)d_in[14];
    const float* v3 = (const float*)d_in[15];
    const float* mw = (const float*)d_in[16];
    const float* mb = (const float*)d_in[17];
    float* outp = (float*)d_out;

    // ws layout
    char* p = (char*)d_ws;
    __hip_bfloat16* h1g = (__hip_bfloat16*)p;  p += (size_t)BATCH * 3364 * 64 * 2; // 13.8 MB
    float* mask = (float*)p;                   p += (size_t)BATCH * HW * 4;        // 0.4 MB
    __hip_bfloat16* w1p = (__hip_bfloat16*)p;  p += 16384 * 2;
    __hip_bfloat16* w2p = (__hip_bfloat16*)p;  p += 36864 * 2;
    __hip_bfloat16* w3p = (__hip_bfloat16*)p;  p += 16384 * 2;
    float* tabs = (float*)p;
    float* sc1 = tabs;       float* sh1 = tabs + 64;
    float* sc2 = tabs + 128; float* sh2 = tabs + 192;
    float* sc3 = tabs + 256; float* sh3 = tabs + 512;

    kbn<<<dim3(1), dim3(384), 0, stream>>>(g1, b1, m1, v1, g2, b2, m2, v2,
                                           g3, b3, m3, v3, tabs);
    kw_pack<<<dim3(272), dim3(256), 0, stream>>>(w1, w2, w3, w1p, w2p, w3p);

    k1_mfma<<<dim3(49, BATCH), dim3(256), 0, stream>>>(x, w1p, sc1, sh1, mw, mb,
                                                       h1g, mask);

    int npad = BATCH * 3364;
    k1b_dilate<<<dim3((npad + 255) / 256), dim3(256), 0, stream>>>(mask, h1g);

    k23<<<dim3(HH / 2, BATCH), dim3(256), 0, stream>>>(h1g, w2p, w3p, sc2, sh2,
                                                       sc3, sh3, x, mask, outp);
}